// Round 1
// baseline (191.681 us; speedup 1.0000x reference)
//
#include <hip/hip_runtime.h>
#include <math.h>

typedef __bf16 bf16x8 __attribute__((ext_vector_type(8)));
typedef float f32x4 __attribute__((ext_vector_type(4)));

#define MFMA16(a, b, c) __builtin_amdgcn_mfma_f32_16x16x32_bf16(a, b, c, 0, 0, 0)

static constexpr int M_TOT = 8192;   // B*S
static constexpr int DIN = 4096;
static constexpr int DOUT = 4096;
static constexpr int RNK = 64;

__device__ inline unsigned short f2bf(float f) {
    union { float f; unsigned u; } v; v.f = f;
    unsigned r = v.u + 0x7FFFu + ((v.u >> 16) & 1u);   // round-to-nearest-even
    return (unsigned short)(r >> 16);
}

// ---------------------------------------------------------------------------
// Prep: lora_A [64][4096] -> Abf (bf16, same layout) and Atbf (bf16, [4096][64])
//       lora_B [4096][64] -> Bbf (bf16, same layout)
// ---------------------------------------------------------------------------
__global__ __launch_bounds__(256) void k_prep(const float* __restrict__ A,
                                              const float* __restrict__ B,
                                              unsigned short* __restrict__ Abf,
                                              unsigned short* __restrict__ Atbf,
                                              unsigned short* __restrict__ Bbf) {
    int i = blockIdx.x * 256 + threadIdx.x;          // 0 .. 262143
    unsigned short ab = f2bf(A[i]);
    Abf[i] = ab;
    int r = i >> 12, c = i & 4095;                   // A is [64][4096]
    Atbf[c * RNK + r] = ab;
    Bbf[i] = f2bf(B[i]);
}

// ---------------------------------------------------------------------------
// K1: xa = x @ lora_A^T   [8192 x 64], bf16 output.
// Block = 512 threads (8 waves). Block owns a 16-row M tile; K=4096 split
// 8 ways across waves (512 each); f32 partials reduced in LDS.
// ---------------------------------------------------------------------------
__global__ __launch_bounds__(512) void k1_xa(const float* __restrict__ x,
                                             const unsigned short* __restrict__ Abf,
                                             unsigned short* __restrict__ xabf) {
    __shared__ float red[8][1024];                   // 8 waves x (16m x 64r) = 32 KB
    int tid = threadIdx.x;
    int wid = tid >> 6, lane = tid & 63;
    int row = lane & 15, kq = lane >> 4;
    int m0 = blockIdx.x * 16;

    f32x4 acc0 = {0.f, 0.f, 0.f, 0.f};
    f32x4 acc1 = acc0, acc2 = acc0, acc3 = acc0;

    const float* xp = x + (size_t)(m0 + row) * DIN + wid * 512 + kq * 8;
    const unsigned short* ap = Abf + (size_t)row * DIN + wid * 512 + kq * 8;

    #pragma unroll 4
    for (int ks = 0; ks < 512; ks += 32) {
        f32x4 x0 = *(const f32x4*)(xp + ks);
        f32x4 x1 = *(const f32x4*)(xp + ks + 4);
        bf16x8 af;
        #pragma unroll
        for (int j = 0; j < 4; ++j) { af[j] = (__bf16)x0[j]; af[j + 4] = (__bf16)x1[j]; }
        acc0 = MFMA16(af, *(const bf16x8*)(ap + ks), acc0);
        acc1 = MFMA16(af, *(const bf16x8*)(ap + 16 * DIN + ks), acc1);
        acc2 = MFMA16(af, *(const bf16x8*)(ap + 32 * DIN + ks), acc2);
        acc3 = MFMA16(af, *(const bf16x8*)(ap + 48 * DIN + ks), acc3);
    }

    int mb = kq * 4;                                  // C: row = (lane>>4)*4 + reg
    #pragma unroll
    for (int rg = 0; rg < 4; ++rg) {
        red[wid][(mb + rg) * 64 + row]      = acc0[rg];
        red[wid][(mb + rg) * 64 + 16 + row] = acc1[rg];
        red[wid][(mb + rg) * 64 + 32 + row] = acc2[rg];
        red[wid][(mb + rg) * 64 + 48 + row] = acc3[rg];
    }
    __syncthreads();

    #pragma unroll
    for (int e = tid; e < 1024; e += 512) {
        float s = 0.f;
        #pragma unroll
        for (int w = 0; w < 8; ++w) s += red[w][e];
        xabf[(size_t)m0 * RNK + e] = f2bf(s);
    }
}

// ---------------------------------------------------------------------------
// K2: mag_scale[o] = magnitude[o] / (||base_weight[o,:] + 2*(B@A)[o,:]||_2 + eps)
// Block = 256 threads (4 waves). Block owns 16 output rows; each wave covers a
// quarter of the 4096 i-range. B@A tiles via MFMA, squared-norm fused.
// ---------------------------------------------------------------------------
__global__ __launch_bounds__(256) void k2_norm(const float* __restrict__ bw,
                                               const unsigned short* __restrict__ Bbf,
                                               const unsigned short* __restrict__ Atbf,
                                               const float* __restrict__ mag,
                                               float* __restrict__ mscale) {
    __shared__ float part[4][16];
    int tid = threadIdx.x;
    int wid = tid >> 6, lane = tid & 63;
    int row = lane & 15, kq = lane >> 4;
    int o0 = blockIdx.x * 16;

    // A-operand (lora_B rows) is loop-invariant: hoist.
    bf16x8 a0 = *(const bf16x8*)(Bbf + (size_t)(o0 + row) * RNK + kq * 8);
    bf16x8 a1 = *(const bf16x8*)(Bbf + (size_t)(o0 + row) * RNK + 32 + kq * 8);

    float nacc[4] = {0.f, 0.f, 0.f, 0.f};
    int ob = o0 + kq * 4;

    #pragma unroll 2
    for (int ii = 0; ii < 64; ++ii) {
        int i0 = wid * 1024 + ii * 16;
        bf16x8 b0 = *(const bf16x8*)(Atbf + (size_t)(i0 + row) * RNK + kq * 8);
        bf16x8 b1 = *(const bf16x8*)(Atbf + (size_t)(i0 + row) * RNK + 32 + kq * 8);
        f32x4 d = {0.f, 0.f, 0.f, 0.f};
        d = MFMA16(a0, b0, d);
        d = MFMA16(a1, b1, d);
        #pragma unroll
        for (int rg = 0; rg < 4; ++rg) {
            float w = bw[(size_t)(ob + rg) * DIN + i0 + row] + 2.0f * d[rg];
            nacc[rg] += w * w;
        }
    }

    // reduce across the 16 lanes of each quarter-group (xor stays in-group)
    #pragma unroll
    for (int m = 1; m < 16; m <<= 1) {
        #pragma unroll
        for (int rg = 0; rg < 4; ++rg) nacc[rg] += __shfl_xor(nacc[rg], m, 64);
    }
    if (row == 0) {
        #pragma unroll
        for (int rg = 0; rg < 4; ++rg) part[wid][kq * 4 + rg] = nacc[rg];
    }
    __syncthreads();
    if (tid < 16) {
        float n2 = part[0][tid] + part[1][tid] + part[2][tid] + part[3][tid];
        mscale[o0 + tid] = mag[o0 + tid] / (sqrtf(n2) + 1e-8f);
    }
}

// ---------------------------------------------------------------------------
// K3: out = (base_output + 2 * xa @ lora_B^T) * mag_scale
// Block = 256 threads (4 waves). Block tile: 16 M x 256 N; each wave 16x64.
// ---------------------------------------------------------------------------
__global__ __launch_bounds__(256) void k3_out(const float* __restrict__ base,
                                              const unsigned short* __restrict__ xabf,
                                              const unsigned short* __restrict__ Bbf,
                                              const float* __restrict__ mscale,
                                              float* __restrict__ out) {
    int tid = threadIdx.x;
    int wid = tid >> 6, lane = tid & 63;
    int row = lane & 15, kq = lane >> 4;
    int m0 = blockIdx.x * 16;
    int n0 = blockIdx.y * 256 + wid * 64;

    bf16x8 a0 = *(const bf16x8*)(xabf + (size_t)(m0 + row) * RNK + kq * 8);
    bf16x8 a1 = *(const bf16x8*)(xabf + (size_t)(m0 + row) * RNK + 32 + kq * 8);
    int om = m0 + kq * 4;

    #pragma unroll
    for (int nt = 0; nt < 4; ++nt) {
        int n = n0 + nt * 16;
        bf16x8 b0 = *(const bf16x8*)(Bbf + (size_t)(n + row) * RNK + kq * 8);
        bf16x8 b1 = *(const bf16x8*)(Bbf + (size_t)(n + row) * RNK + 32 + kq * 8);
        f32x4 acc = {0.f, 0.f, 0.f, 0.f};
        acc = MFMA16(a0, b0, acc);
        acc = MFMA16(a1, b1, acc);
        float ms = mscale[n + row];
        #pragma unroll
        for (int rg = 0; rg < 4; ++rg) {
            size_t idx = (size_t)(om + rg) * DOUT + n + row;
            out[idx] = (base[idx] + 2.0f * acc[rg]) * ms;
        }
    }
}

extern "C" void kernel_launch(void* const* d_in, const int* in_sizes, int n_in,
                              void* d_out, int out_size, void* d_ws, size_t ws_size,
                              hipStream_t stream) {
    const float* x    = (const float*)d_in[0];   // [2,4096,4096]
    const float* base = (const float*)d_in[1];   // [2,4096,4096]
    const float* bw   = (const float*)d_in[2];   // [4096,4096]
    const float* lA   = (const float*)d_in[3];   // [64,4096]
    const float* lB   = (const float*)d_in[4];   // [4096,64]
    const float* mag  = (const float*)d_in[5];   // [4096]
    float* out = (float*)d_out;

    char* ws = (char*)d_ws;
    unsigned short* Abf  = (unsigned short*)(ws);                   // 512 KB
    unsigned short* Atbf = (unsigned short*)(ws + (512u << 10));    // 512 KB
    unsigned short* Bbf  = (unsigned short*)(ws + (1024u << 10));   // 512 KB
    unsigned short* xabf = (unsigned short*)(ws + (1536u << 10));   // 1 MB
    float*          msc  = (float*)(ws + (2560u << 10));            // 16 KB

    hipLaunchKernelGGL(k_prep, dim3(1024), dim3(256), 0, stream, lA, lB, Abf, Atbf, Bbf);
    hipLaunchKernelGGL(k1_xa, dim3(M_TOT / 16), dim3(512), 0, stream, x, Abf, xabf);
    hipLaunchKernelGGL(k2_norm, dim3(DOUT / 16), dim3(256), 0, stream, bw, Bbf, Atbf, mag, msc);
    hipLaunchKernelGGL(k3_out, dim3(M_TOT / 16, DOUT / 256), dim3(256), 0, stream,
                       base, xabf, Bbf, msc, out);
}

// Round 2
// 162.221 us; speedup vs baseline: 1.1816x; 1.1816x over previous
//
#include <hip/hip_runtime.h>
#include <math.h>

typedef __bf16 bf16x8 __attribute__((ext_vector_type(8)));
typedef float f32x4 __attribute__((ext_vector_type(4)));

#define MFMA16(a, b, c) __builtin_amdgcn_mfma_f32_16x16x32_bf16(a, b, c, 0, 0, 0)

static constexpr int M_TOT = 8192;   // B*S
static constexpr int DIN = 4096;
static constexpr int DOUT = 4096;
static constexpr int RNK = 64;

__device__ inline unsigned short f2bf(float f) {
    union { float f; unsigned u; } v; v.f = f;
    unsigned r = v.u + 0x7FFFu + ((v.u >> 16) & 1u);   // round-to-nearest-even
    return (unsigned short)(r >> 16);
}

// ---------------------------------------------------------------------------
// Prep: lora_A [64][4096] -> Abf (bf16, same layout) and Atbf (bf16, [4096][64])
//       lora_B [4096][64] -> Bbf (bf16, same layout)
// ---------------------------------------------------------------------------
__global__ __launch_bounds__(256) void k_prep(const float* __restrict__ A,
                                              const float* __restrict__ B,
                                              unsigned short* __restrict__ Abf,
                                              unsigned short* __restrict__ Atbf,
                                              unsigned short* __restrict__ Bbf) {
    int i = blockIdx.x * 256 + threadIdx.x;          // 0 .. 262143
    unsigned short ab = f2bf(A[i]);
    Abf[i] = ab;
    int r = i >> 12, c = i & 4095;                   // A is [64][4096]
    Atbf[c * RNK + r] = ab;
    Bbf[i] = f2bf(B[i]);
}

// ---------------------------------------------------------------------------
// K1: xa = x @ lora_A^T   [8192 x 64], bf16 output.  (unchanged this round)
// ---------------------------------------------------------------------------
__global__ __launch_bounds__(512) void k1_xa(const float* __restrict__ x,
                                             const unsigned short* __restrict__ Abf,
                                             unsigned short* __restrict__ xabf) {
    __shared__ float red[8][1024];                   // 8 waves x (16m x 64r) = 32 KB
    int tid = threadIdx.x;
    int wid = tid >> 6, lane = tid & 63;
    int row = lane & 15, kq = lane >> 4;
    int m0 = blockIdx.x * 16;

    f32x4 acc0 = {0.f, 0.f, 0.f, 0.f};
    f32x4 acc1 = acc0, acc2 = acc0, acc3 = acc0;

    const float* xp = x + (size_t)(m0 + row) * DIN + wid * 512 + kq * 8;
    const unsigned short* ap = Abf + (size_t)row * DIN + wid * 512 + kq * 8;

    #pragma unroll 4
    for (int ks = 0; ks < 512; ks += 32) {
        f32x4 x0 = *(const f32x4*)(xp + ks);
        f32x4 x1 = *(const f32x4*)(xp + ks + 4);
        bf16x8 af;
        #pragma unroll
        for (int j = 0; j < 4; ++j) { af[j] = (__bf16)x0[j]; af[j + 4] = (__bf16)x1[j]; }
        acc0 = MFMA16(af, *(const bf16x8*)(ap + ks), acc0);
        acc1 = MFMA16(af, *(const bf16x8*)(ap + 16 * DIN + ks), acc1);
        acc2 = MFMA16(af, *(const bf16x8*)(ap + 32 * DIN + ks), acc2);
        acc3 = MFMA16(af, *(const bf16x8*)(ap + 48 * DIN + ks), acc3);
    }

    int mb = kq * 4;                                  // C: row = (lane>>4)*4 + reg
    #pragma unroll
    for (int rg = 0; rg < 4; ++rg) {
        red[wid][(mb + rg) * 64 + row]      = acc0[rg];
        red[wid][(mb + rg) * 64 + 16 + row] = acc1[rg];
        red[wid][(mb + rg) * 64 + 32 + row] = acc2[rg];
        red[wid][(mb + rg) * 64 + 48 + row] = acc3[rg];
    }
    __syncthreads();

    #pragma unroll
    for (int e = tid; e < 1024; e += 512) {
        float s = 0.f;
        #pragma unroll
        for (int w = 0; w < 8; ++w) s += red[w][e];
        xabf[(size_t)m0 * RNK + e] = f2bf(s);
    }
}

// ---------------------------------------------------------------------------
// K2: partial squared row-norms of (base_weight + 2*B@A).
// Grid = 256 o-tiles x 4 i-quarters = 1024 blocks, 256 threads (4 waves).
// Operands swapped (A-op = Atbf rows, B-op = Bbf rows) so each lane holds
// delta[o][i..i+3] -> one f32x4 load of base_weight per MFMA pair.
// Deterministic: block (o-tile,q) exclusively owns nrm2p[q*4096 + o0..o0+15].
// ---------------------------------------------------------------------------
__global__ __launch_bounds__(256) void k2_norm(const float* __restrict__ bw,
                                               const unsigned short* __restrict__ Bbf,
                                               const unsigned short* __restrict__ Atbf,
                                               float* __restrict__ nrm2p) {
    __shared__ float part[4][16];
    int tid = threadIdx.x;
    int wid = tid >> 6, lane = tid & 63;
    int row = lane & 15, kq = lane >> 4;
    int o0 = (blockIdx.x >> 2) * 16;
    int q  = blockIdx.x & 3;

    // B-operand: lora_B rows (o = lane&15), loop-invariant.
    bf16x8 b0 = *(const bf16x8*)(Bbf + (size_t)(o0 + row) * RNK + kq * 8);
    bf16x8 b1 = *(const bf16x8*)(Bbf + (size_t)(o0 + row) * RNK + 32 + kq * 8);

    float nacc = 0.f;
    const float* bwp = bw + (size_t)(o0 + row) * DIN + q * 1024 + wid * 256 + kq * 4;
    const unsigned short* atp = Atbf + (size_t)(q * 1024 + wid * 256 + row) * RNK + kq * 8;

    #pragma unroll 4
    for (int ii = 0; ii < 16; ++ii) {
        bf16x8 a0 = *(const bf16x8*)(atp + (size_t)ii * 16 * RNK);
        bf16x8 a1 = *(const bf16x8*)(atp + (size_t)ii * 16 * RNK + 32);
        f32x4 d = {0.f, 0.f, 0.f, 0.f};
        d = MFMA16(a0, b0, d);                       // lane: delta[o=row][i = base + kq*4 + rg]
        d = MFMA16(a1, b1, d);
        f32x4 wv = *(const f32x4*)(bwp + ii * 16);
        #pragma unroll
        for (int rg = 0; rg < 4; ++rg) {
            float w = wv[rg] + 2.0f * d[rg];
            nacc += w * w;
        }
    }

    // reduce across the 4 kq groups (lanes row, row+16, row+32, row+48)
    nacc += __shfl_xor(nacc, 16, 64);
    nacc += __shfl_xor(nacc, 32, 64);
    if (kq == 0) part[wid][row] = nacc;
    __syncthreads();
    if (tid < 16) {
        nrm2p[q * DOUT + o0 + tid] =
            part[0][tid] + part[1][tid] + part[2][tid] + part[3][tid];
    }
}

// K2b: mscale[o] = mag[o] / (sqrt(sum_q nrm2p[q][o]) + eps)
__global__ __launch_bounds__(256) void k2b_scale(const float* __restrict__ nrm2p,
                                                 const float* __restrict__ mag,
                                                 float* __restrict__ mscale) {
    int o = blockIdx.x * 256 + threadIdx.x;
    float n2 = nrm2p[o] + nrm2p[DOUT + o] + nrm2p[2 * DOUT + o] + nrm2p[3 * DOUT + o];
    mscale[o] = mag[o] / (sqrtf(n2) + 1e-8f);
}

// ---------------------------------------------------------------------------
// K3: out = (base_output + 2 * xa @ lora_B^T) * mag_scale
// Block = 256 threads (4 waves), tile 16m x 256n. Operands swapped so lane
// holds 4 consecutive n; delta goes through padded LDS; epilogue is fully
// coalesced: every wave instruction moves 1 KB contiguous from one row.
// ---------------------------------------------------------------------------
__global__ __launch_bounds__(256) void k3_out(const float* __restrict__ base,
                                              const unsigned short* __restrict__ xabf,
                                              const unsigned short* __restrict__ Bbf,
                                              const float* __restrict__ mscale,
                                              float* __restrict__ out) {
    __shared__ float dls[16][260];                   // +4 pad -> 2-way bank alias (free)
    int tid = threadIdx.x;
    int wid = tid >> 6, lane = tid & 63;
    int row = lane & 15, kq = lane >> 4;
    int m0 = blockIdx.x * 16;
    int n0 = blockIdx.y * 256;

    // B-operand: xa rows (m = lane&15), loop-invariant.
    bf16x8 xb0 = *(const bf16x8*)(xabf + (size_t)(m0 + row) * RNK + kq * 8);
    bf16x8 xb1 = *(const bf16x8*)(xabf + (size_t)(m0 + row) * RNK + 32 + kq * 8);

    #pragma unroll
    for (int nt = 0; nt < 4; ++nt) {
        int n = n0 + wid * 64 + nt * 16;
        bf16x8 a0 = *(const bf16x8*)(Bbf + (size_t)(n + row) * RNK + kq * 8);
        bf16x8 a1 = *(const bf16x8*)(Bbf + (size_t)(n + row) * RNK + 32 + kq * 8);
        f32x4 acc = {0.f, 0.f, 0.f, 0.f};
        acc = MFMA16(a0, xb0, acc);                  // lane: delta[m=row][nloc = kq*4+rg]
        acc = MFMA16(a1, xb1, acc);
        *(f32x4*)&dls[row][wid * 64 + nt * 16 + kq * 4] = acc;
    }
    __syncthreads();

    f32x4 msv = *(const f32x4*)(mscale + n0 + lane * 4);
    #pragma unroll
    for (int r = 0; r < 4; ++r) {
        int m = wid * 4 + r;
        f32x4 d = *(const f32x4*)&dls[m][lane * 4];
        size_t gidx = (size_t)(m0 + m) * DOUT + n0 + lane * 4;
        f32x4 b = *(const f32x4*)(base + gidx);
        f32x4 o;
        #pragma unroll
        for (int j = 0; j < 4; ++j) o[j] = (b[j] + 2.0f * d[j]) * msv[j];
        *(f32x4*)(out + gidx) = o;
    }
}

extern "C" void kernel_launch(void* const* d_in, const int* in_sizes, int n_in,
                              void* d_out, int out_size, void* d_ws, size_t ws_size,
                              hipStream_t stream) {
    const float* x    = (const float*)d_in[0];   // [2,4096,4096]
    const float* base = (const float*)d_in[1];   // [2,4096,4096]
    const float* bw   = (const float*)d_in[2];   // [4096,4096]
    const float* lA   = (const float*)d_in[3];   // [64,4096]
    const float* lB   = (const float*)d_in[4];   // [4096,64]
    const float* mag  = (const float*)d_in[5];   // [4096]
    float* out = (float*)d_out;

    char* ws = (char*)d_ws;
    unsigned short* Abf  = (unsigned short*)(ws);                   // 512 KB (k1 only)
    unsigned short* Atbf = (unsigned short*)(ws + (512u << 10));    // 512 KB
    unsigned short* Bbf  = (unsigned short*)(ws + (1024u << 10));   // 512 KB
    unsigned short* xabf = (unsigned short*)(ws + (1536u << 10));   // 1 MB
    float*          msc  = (float*)(ws + (2560u << 10));            // 16 KB
    float*          nrm2p = (float*)(ws);                           // 64 KB, aliases Abf
                                                                    // (dead after k1)

    hipLaunchKernelGGL(k_prep, dim3(1024), dim3(256), 0, stream, lA, lB, Abf, Atbf, Bbf);
    hipLaunchKernelGGL(k1_xa, dim3(M_TOT / 16), dim3(512), 0, stream, x, Abf, xabf);
    hipLaunchKernelGGL(k2_norm, dim3((DOUT / 16) * 4), dim3(256), 0, stream,
                       bw, Bbf, Atbf, nrm2p);
    hipLaunchKernelGGL(k2b_scale, dim3(DOUT / 256), dim3(256), 0, stream, nrm2p, mag, msc);
    hipLaunchKernelGGL(k3_out, dim3(M_TOT / 16, DOUT / 256), dim3(256), 0, stream,
                       base, xabf, Bbf, msc, out);
}